// Round 4
// baseline (545.713 us; speedup 1.0000x reference)
//
#include <hip/hip_runtime.h>
#include <hip/hip_bf16.h>

#define D 128

#define PW 132   // LDS row pitch for W tiles (float4-aligned)
#define PX 129   // LDS row pitch for transposed activation tiles

// ---------------------------------------------------------------------------
// CSR build: deg count -> exclusive scan -> fill
// ---------------------------------------------------------------------------
__global__ void count_deg(const int* __restrict__ ei, int* __restrict__ deg, int E) {
    int e = blockIdx.x * 256 + threadIdx.x;
    if (e < E) atomicAdd(&deg[ei[E + e]], 1);
}

__global__ __launch_bounds__(256) void scan_kernel(const int* __restrict__ deg,
                                                   int* __restrict__ rowstart,
                                                   int* __restrict__ cursor, int n) {
    __shared__ int tsum[257];
    int tid = threadIdx.x;
    int chunk = (n + 255) / 256;
    int lo = tid * chunk;
    int hi = lo + chunk; if (hi > n) hi = n;
    int s = 0;
    for (int i = lo; i < hi; ++i) s += deg[i];
    tsum[tid] = s;
    __syncthreads();
    if (tid == 0) {
        int run = 0;
        for (int i = 0; i < 256; ++i) { int t = tsum[i]; tsum[i] = run; run += t; }
        tsum[256] = run;
    }
    __syncthreads();
    int run = tsum[tid];
    for (int i = lo; i < hi; ++i) {
        rowstart[i] = run; cursor[i] = run; run += deg[i];
    }
    if (tid == 0) rowstart[n] = tsum[256];
}

__global__ void fill_csr(const int* __restrict__ ei, int* __restrict__ cursor,
                         int* __restrict__ csr, int E) {
    int e = blockIdx.x * 256 + threadIdx.x;
    if (e < E) {
        int s = ei[e];
        int d = ei[E + e];
        int p = atomicAdd(&cursor[d], 1);
        csr[p] = s;
    }
}

// ---------------------------------------------------------------------------
// GEMM1: m_nodes = x @ W_msg + b_msg   (N x 128) @ (128 x 128)
// 128-row tile per block, 256 threads, 8x8 accum per thread, fp32 VALU.
// ---------------------------------------------------------------------------
__global__ __launch_bounds__(256, 1) void gemm_msg(const float* __restrict__ x,
                                                   const float* __restrict__ W,
                                                   const float* __restrict__ b,
                                                   float* __restrict__ out, int n) {
    __shared__ __align__(16) float Ws[D * PW];
    __shared__ __align__(16) float Ts[D * PX];
    const int tid = threadIdx.x;
    const int R0 = blockIdx.x * 128;

    // stage W (row-major) and x^T (Ts[col][row])
    for (int t = 0; t < 64; ++t) {
        int e = t * 256 + tid;
        int r = e >> 7, c = e & 127;
        Ws[r * PW + c] = W[e];
        int gr = R0 + r; if (gr >= n) gr = n - 1;
        Ts[c * PX + r] = x[(long)gr * D + c];
    }
    __syncthreads();

    const int tr = tid >> 4, tc = tid & 15;
    const int r0 = tr * 8, c0 = tc * 8;
    float acc[8][8];
#pragma unroll
    for (int i = 0; i < 8; ++i)
#pragma unroll
        for (int j = 0; j < 8; ++j) acc[i][j] = 0.f;

    for (int k = 0; k < D; ++k) {
        float4 wa = *(const float4*)&Ws[k * PW + c0];
        float4 wb = *(const float4*)&Ws[k * PW + c0 + 4];
        float xs[8];
#pragma unroll
        for (int i = 0; i < 8; ++i) xs[i] = Ts[k * PX + r0 + i];
#pragma unroll
        for (int i = 0; i < 8; ++i) {
            acc[i][0] += xs[i] * wa.x; acc[i][1] += xs[i] * wa.y;
            acc[i][2] += xs[i] * wa.z; acc[i][3] += xs[i] * wa.w;
            acc[i][4] += xs[i] * wb.x; acc[i][5] += xs[i] * wb.y;
            acc[i][6] += xs[i] * wb.z; acc[i][7] += xs[i] * wb.w;
        }
    }

    float bj[8];
#pragma unroll
    for (int j = 0; j < 8; ++j) bj[j] = b[c0 + j];
#pragma unroll
    for (int i = 0; i < 8; ++i) {
        int row = R0 + r0 + i;
        if (row < n) {
            float4 o0, o1;
            o0.x = acc[i][0] + bj[0]; o0.y = acc[i][1] + bj[1];
            o0.z = acc[i][2] + bj[2]; o0.w = acc[i][3] + bj[3];
            o1.x = acc[i][4] + bj[4]; o1.y = acc[i][5] + bj[5];
            o1.z = acc[i][6] + bj[6]; o1.w = acc[i][7] + bj[7];
            *(float4*)&out[(long)row * D + c0] = o0;
            *(float4*)&out[(long)row * D + c0 + 4] = o1;
        }
    }
}

// ---------------------------------------------------------------------------
// aggr[n] = sum over incoming edges of m_nodes[src].  One 64-lane wave per
// node; float2 per lane; gather-only (no float atomics).
// ---------------------------------------------------------------------------
__global__ __launch_bounds__(256) void aggr_kernel(const float* __restrict__ mn,
                                                   const int* __restrict__ rowstart,
                                                   const int* __restrict__ csr,
                                                   float* __restrict__ aggr, int n) {
    int gw = (blockIdx.x * 256 + threadIdx.x) >> 6;
    int lane = threadIdx.x & 63;
    if (gw >= n) return;
    int rs = rowstart[gw], re = rowstart[gw + 1];
    float ax = 0.f, ay = 0.f, bx = 0.f, by = 0.f;
    int i = rs;
    for (; i + 1 < re; i += 2) {
        int s0 = csr[i], s1 = csr[i + 1];
        float2 v0 = *(const float2*)&mn[(long)s0 * D + lane * 2];
        float2 v1 = *(const float2*)&mn[(long)s1 * D + lane * 2];
        ax += v0.x; ay += v0.y; bx += v1.x; by += v1.y;
    }
    if (i < re) {
        int s0 = csr[i];
        float2 v0 = *(const float2*)&mn[(long)s0 * D + lane * 2];
        ax += v0.x; ay += v0.y;
    }
    float2 o; o.x = ax + bx; o.y = ay + by;
    *(float2*)&aggr[(long)gw * D + lane * 2] = o;
}

// ---------------------------------------------------------------------------
// Fused update: conv_out = [x, aggr] @ W_upd + b_upd
//               gate     = sigmoid([conv_out, imp] @ W_gate + b_gate)
//               out      = gate*conv_out + (1-gate)*x
//               p_imp    = out @ W_imp + b_imp
// 128-row tile per block, 256 threads, 8x8 per thread.
// ---------------------------------------------------------------------------
__global__ __launch_bounds__(256, 1) void fused_update(
        const float* __restrict__ x, const float* __restrict__ aggr,
        const float* __restrict__ imp,
        const float* __restrict__ W_upd, const float* __restrict__ b_upd,
        const float* __restrict__ W_gate, const float* __restrict__ b_gate,
        const float* __restrict__ W_imp, const float* __restrict__ b_imp,
        float* __restrict__ out, int n) {
    __shared__ __align__(16) float Ws[D * PW];
    __shared__ __align__(16) float Ts[D * PX];
    const int tid = threadIdx.x;
    const int R0 = blockIdx.x * 128;
    const int tr = tid >> 4, tc = tid & 15;
    const int r0 = tr * 8, c0 = tc * 8;

    float acc[8][8];
#pragma unroll
    for (int i = 0; i < 8; ++i)
#pragma unroll
        for (int j = 0; j < 8; ++j) acc[i][j] = 0.f;

    // ---- Phase A: acc += x @ W_upd[0:128] ----
    for (int t = 0; t < 64; ++t) {
        int e = t * 256 + tid;
        int r = e >> 7, c = e & 127;
        Ws[r * PW + c] = W_upd[e];
        int gr = R0 + r; if (gr >= n) gr = n - 1;
        Ts[c * PX + r] = x[(long)gr * D + c];
    }
    __syncthreads();
    for (int k = 0; k < D; ++k) {
        float4 wa = *(const float4*)&Ws[k * PW + c0];
        float4 wb = *(const float4*)&Ws[k * PW + c0 + 4];
        float xs[8];
#pragma unroll
        for (int i = 0; i < 8; ++i) xs[i] = Ts[k * PX + r0 + i];
#pragma unroll
        for (int i = 0; i < 8; ++i) {
            acc[i][0] += xs[i] * wa.x; acc[i][1] += xs[i] * wa.y;
            acc[i][2] += xs[i] * wa.z; acc[i][3] += xs[i] * wa.w;
            acc[i][4] += xs[i] * wb.x; acc[i][5] += xs[i] * wb.y;
            acc[i][6] += xs[i] * wb.z; acc[i][7] += xs[i] * wb.w;
        }
    }
    __syncthreads();

    // ---- Phase B: acc += aggr @ W_upd[128:256] ----
    for (int t = 0; t < 64; ++t) {
        int e = t * 256 + tid;
        int r = e >> 7, c = e & 127;
        Ws[r * PW + c] = W_upd[128 * D + e];
        int gr = R0 + r; if (gr >= n) gr = n - 1;
        Ts[c * PX + r] = aggr[(long)gr * D + c];
    }
    __syncthreads();
    for (int k = 0; k < D; ++k) {
        float4 wa = *(const float4*)&Ws[k * PW + c0];
        float4 wb = *(const float4*)&Ws[k * PW + c0 + 4];
        float xs[8];
#pragma unroll
        for (int i = 0; i < 8; ++i) xs[i] = Ts[k * PX + r0 + i];
#pragma unroll
        for (int i = 0; i < 8; ++i) {
            acc[i][0] += xs[i] * wa.x; acc[i][1] += xs[i] * wa.y;
            acc[i][2] += xs[i] * wa.z; acc[i][3] += xs[i] * wa.w;
            acc[i][4] += xs[i] * wb.x; acc[i][5] += xs[i] * wb.y;
            acc[i][6] += xs[i] * wb.z; acc[i][7] += xs[i] * wb.w;
        }
    }
    __syncthreads();   // everyone done reading Ts/Ws before overwrite

    // ---- Phase C: conv_out = acc + b_upd; stash conv_out^T; stage W_gate ----
#pragma unroll
    for (int j = 0; j < 8; ++j) {
        float bj = b_upd[c0 + j];
#pragma unroll
        for (int i = 0; i < 8; ++i) acc[i][j] += bj;
    }
#pragma unroll
    for (int i = 0; i < 8; ++i)
#pragma unroll
        for (int j = 0; j < 8; ++j)
            Ts[(c0 + j) * PX + r0 + i] = acc[i][j];
    for (int t = 0; t < 64; ++t) {
        int e = t * 256 + tid;
        int r = e >> 7, c = e & 127;
        Ws[r * PW + c] = W_gate[e];       // rows 0..127 of W_gate
    }
    __syncthreads();

    // ---- Phase D: g = conv_out @ W_gate[0:128] ----
    float g[8][8];
#pragma unroll
    for (int i = 0; i < 8; ++i)
#pragma unroll
        for (int j = 0; j < 8; ++j) g[i][j] = 0.f;
    for (int k = 0; k < D; ++k) {
        float4 wa = *(const float4*)&Ws[k * PW + c0];
        float4 wb = *(const float4*)&Ws[k * PW + c0 + 4];
        float xs[8];
#pragma unroll
        for (int i = 0; i < 8; ++i) xs[i] = Ts[k * PX + r0 + i];
#pragma unroll
        for (int i = 0; i < 8; ++i) {
            g[i][0] += xs[i] * wa.x; g[i][1] += xs[i] * wa.y;
            g[i][2] += xs[i] * wa.z; g[i][3] += xs[i] * wa.w;
            g[i][4] += xs[i] * wb.x; g[i][5] += xs[i] * wb.y;
            g[i][6] += xs[i] * wb.z; g[i][7] += xs[i] * wb.w;
        }
    }

    // ---- Phase E: gate, mix, store out ----
    float wgl[8], bg[8], wim[8];
#pragma unroll
    for (int j = 0; j < 8; ++j) {
        wgl[j] = W_gate[128 * D + c0 + j];
        bg[j]  = b_gate[c0 + j];
        wim[j] = W_imp[c0 + j];
    }
    const float bi = b_imp[0];

#pragma unroll
    for (int i = 0; i < 8; ++i) {
        int row = R0 + r0 + i;
        int crow = row < n ? row : n - 1;
        float iv = imp[crow];
        float4 xv0 = *(const float4*)&x[(long)crow * D + c0];
        float4 xv1 = *(const float4*)&x[(long)crow * D + c0 + 4];
        float xr[8] = {xv0.x, xv0.y, xv0.z, xv0.w, xv1.x, xv1.y, xv1.z, xv1.w};
#pragma unroll
        for (int j = 0; j < 8; ++j) {
            float z = g[i][j] + iv * wgl[j] + bg[j];
            float s = 1.0f / (1.0f + expf(-z));
            g[i][j] = s * acc[i][j] + (1.0f - s) * xr[j];   // g now holds out
        }
        if (row < n) {
            float4 o0, o1;
            o0.x = g[i][0]; o0.y = g[i][1]; o0.z = g[i][2]; o0.w = g[i][3];
            o1.x = g[i][4]; o1.y = g[i][5]; o1.z = g[i][6]; o1.w = g[i][7];
            *(float4*)&out[(long)row * D + c0] = o0;
            *(float4*)&out[(long)row * D + c0 + 4] = o1;
        }
    }

    // ---- Phase F: p_imp = out @ W_imp + b_imp (reduce across 16 threads/row) ----
#pragma unroll
    for (int i = 0; i < 8; ++i) {
        float pi = 0.f;
#pragma unroll
        for (int j = 0; j < 8; ++j) pi += g[i][j] * wim[j];
#pragma unroll
        for (int m = 8; m >= 1; m >>= 1) pi += __shfl_xor(pi, m, 16);
        int row = R0 + r0 + i;
        if (tc == 0 && row < n) out[(long)n * D + row] = pi + bi;
    }
}

// ---------------------------------------------------------------------------
extern "C" void kernel_launch(void* const* d_in, const int* in_sizes, int n_in,
                              void* d_out, int out_size, void* d_ws, size_t ws_size,
                              hipStream_t stream) {
    const float* x      = (const float*)d_in[0];
    const int*   ei     = (const int*)d_in[1];
    const float* imp    = (const float*)d_in[2];
    const float* W_msg  = (const float*)d_in[3];
    const float* b_msg  = (const float*)d_in[4];
    const float* W_upd  = (const float*)d_in[5];
    const float* b_upd  = (const float*)d_in[6];
    const float* W_gate = (const float*)d_in[7];
    const float* b_gate = (const float*)d_in[8];
    const float* W_imp  = (const float*)d_in[9];
    const float* b_imp  = (const float*)d_in[10];
    float* out = (float*)d_out;

    const int N = in_sizes[0] / D;       // derive from harness (robustness)
    const int E = in_sizes[1] / 2;

    char* ws = (char*)d_ws;
    float* m_nodes  = (float*)ws;  ws += (size_t)N * D * sizeof(float);
    float* aggr     = (float*)ws;  ws += (size_t)N * D * sizeof(float);
    int*   deg      = (int*)ws;    ws += (size_t)N * sizeof(int);
    int*   rowstart = (int*)ws;    ws += (size_t)(N + 1) * sizeof(int);
    int*   cursor   = (int*)ws;    ws += (size_t)N * sizeof(int);
    int*   csr      = (int*)ws;    ws += (size_t)E * sizeof(int);

    hipMemsetAsync(deg, 0, (size_t)N * sizeof(int), stream);

    count_deg<<<(E + 255) / 256, 256, 0, stream>>>(ei, deg, E);
    scan_kernel<<<1, 256, 0, stream>>>(deg, rowstart, cursor, N);
    fill_csr<<<(E + 255) / 256, 256, 0, stream>>>(ei, cursor, csr, E);

    const int nblk = (N + 127) / 128;
    gemm_msg<<<nblk, 256, 0, stream>>>(x, W_msg, b_msg, m_nodes, N);

    aggr_kernel<<<((size_t)N * 64 + 255) / 256, 256, 0, stream>>>(
        m_nodes, rowstart, csr, aggr, N);

    fused_update<<<nblk, 256, 0, stream>>>(x, aggr, imp, W_upd, b_upd,
                                           W_gate, b_gate, W_imp, b_imp,
                                           out, N);
}